// Round 8
// baseline (155.190 us; speedup 1.0000x reference)
//
#include <hip/hip_runtime.h>
#include <math.h>

#define NBINS 256
#define HIST_COPIES 32
#define HIST_BLOCKS 2048
#define GATH_BLOCKS 2048

typedef float vfloat4 __attribute__((ext_vector_type(4)));

__device__ __forceinline__ int quant_idx(float s) {
    // reference: clip(floor((s+1)/2*255), 0, 255)
    float t = floorf((s + 1.0f) * 0.5f * 255.0f);
    t = fminf(fmaxf(t, 0.0f), 255.0f);
    return (int)t;
}

// ---- Pass 1: LDS-privatized histogram -> 32 contention-split global copies
//      + packed-u8 idx store. All plain cached accesses (no nt hints).
template <bool STORE_IDX>
__global__ __launch_bounds__(256) void hist_kernel(
    const float* __restrict__ src, unsigned int* __restrict__ copies,
    unsigned int* __restrict__ idx4_out, int n4, int n) {
    __shared__ unsigned int lh[4][NBINS];
    const int tid = threadIdx.x;
    const int wave = tid >> 6;
    for (int i = tid; i < 4 * NBINS; i += 256) ((unsigned int*)lh)[i] = 0u;
    __syncthreads();

    const int stride = gridDim.x * 256;
    const vfloat4* src4 = (const vfloat4*)src;
    for (int i = blockIdx.x * 256 + tid; i < n4; i += stride) {
        vfloat4 v = src4[i];                       // cached: want src L3-resident
        int i0 = quant_idx(v.x);
        int i1 = quant_idx(v.y);
        int i2 = quant_idx(v.z);
        int i3 = quant_idx(v.w);
        atomicAdd(&lh[wave][i0], 1u);
        atomicAdd(&lh[wave][i1], 1u);
        atomicAdd(&lh[wave][i2], 1u);
        atomicAdd(&lh[wave][i3], 1u);
        if (STORE_IDX) {
            idx4_out[i] = (unsigned int)i0 | ((unsigned int)i1 << 8) |
                          ((unsigned int)i2 << 16) | ((unsigned int)i3 << 24);
        }
    }
    // tail (n % 4) — block 0, folded into its LDS hist before the flush
    if (blockIdx.x == 0 && tid == 0) {
        for (int j = n4 * 4; j < n; ++j) {
            int b = quant_idx(src[j]);
            atomicAdd(&lh[0][b], 1u);
            if (STORE_IDX) ((unsigned char*)idx4_out)[j] = (unsigned char)b;
        }
    }
    __syncthreads();
    // one atomic per bin per block, spread over 32 copies (zeroed by memset)
    unsigned int s = lh[0][tid] + lh[1][tid] + lh[2][tid] + lh[3][tid];
    if (s) atomicAdd(&copies[(blockIdx.x & (HIST_COPIES - 1)) * NBINS + tid], s);
}

// ---- Pass 1b: one block builds the pre-scaled LUT (scan + erff + lower_bound).
__global__ __launch_bounds__(256) void lut_kernel(
    const unsigned int* __restrict__ copies, float* __restrict__ lut_g) {
    __shared__ float ncdf[NBINS];
    __shared__ unsigned int wsum[4];
    const int tid = threadIdx.x;
    const int wave = tid >> 6;
    unsigned int hv = 0;
#pragma unroll
    for (int c = 0; c < HIST_COPIES; ++c) hv += copies[c * NBINS + tid];
    // inclusive scan across 256 threads
    unsigned int v = hv;
    for (int d = 1; d < 64; d <<= 1) {
        unsigned int o = __shfl_up(v, d, 64);
        if ((tid & 63) >= d) v += o;
    }
    if ((tid & 63) == 63) wsum[wave] = v;
    __syncthreads();
    unsigned int add = 0;
    for (int w = 0; w < wave; ++w) add += wsum[w];
    v += add;
    const float total = (float)(wsum[0] + wsum[1] + wsum[2] + wsum[3]);
    const float sv = (float)v / total;

    // linspace(-1,1,256); norm.cdf(x,0,0.2) = 0.5*(1+erf(x/(0.2*sqrt(2))))
    const float x = ((float)tid * 2.0f - 255.0f) / 255.0f;
    const float nc = 0.5f * (1.0f + erff(x * 3.5355339059327378f));
    const float nc255 = 0.5f * (1.0f + erff(3.5355339059327378f));
    ncdf[tid] = nc / nc255;
    __syncthreads();
    // searchsorted side='left' == lower_bound
    int lo = 0, hi = NBINS;
    while (lo < hi) {
        int m = (lo + hi) >> 1;
        if (ncdf[m] < sv) lo = m + 1; else hi = m;
    }
    lut_g[tid] = (float)lo * (2.0f / 255.0f) - 1.0f;  // pre-apply final rescale
}

// ---- Pass 2a: gather via stored u8 indices; LUT loaded from global (1 KiB).
__global__ __launch_bounds__(256) void gather_idx_kernel(
    const unsigned int* __restrict__ idx4, const float* __restrict__ lut_g,
    vfloat4* __restrict__ out, int n4, int n, float* __restrict__ out_flat) {
    __shared__ float luts[NBINS];
    luts[threadIdx.x] = lut_g[threadIdx.x];
    __syncthreads();

    const int stride = gridDim.x * 256;
    for (int i = blockIdx.x * 256 + threadIdx.x; i < n4; i += stride) {
        unsigned int p = idx4[i];                  // cached load: L3-resident
        vfloat4 o;
        o.x = luts[p & 255u];
        o.y = luts[(p >> 8) & 255u];
        o.z = luts[(p >> 16) & 255u];
        o.w = luts[p >> 24];
        out[i] = o;                                // plain store (fills hit 7 TB/s)
    }
    if (blockIdx.x == 0 && threadIdx.x == 0) {
        const unsigned char* ib = (const unsigned char*)idx4;
        for (int j = n4 * 4; j < n; ++j) out_flat[j] = luts[ib[j]];
    }
}

// ---- Pass 2b fallback: recompute idx from source (ws too small for idx).
__global__ __launch_bounds__(256) void gather_src_kernel(
    const float* __restrict__ src, const float* __restrict__ lut_g,
    vfloat4* __restrict__ out, int n4, int n, float* __restrict__ out_flat) {
    __shared__ float luts[NBINS];
    luts[threadIdx.x] = lut_g[threadIdx.x];
    __syncthreads();

    const int stride = gridDim.x * 256;
    const vfloat4* src4 = (const vfloat4*)src;
    for (int i = blockIdx.x * 256 + threadIdx.x; i < n4; i += stride) {
        vfloat4 v = src4[i];
        vfloat4 o;
        o.x = luts[quant_idx(v.x)];
        o.y = luts[quant_idx(v.y)];
        o.z = luts[quant_idx(v.z)];
        o.w = luts[quant_idx(v.w)];
        out[i] = o;
    }
    if (blockIdx.x == 0 && threadIdx.x == 0) {
        for (int j = n4 * 4; j < n; ++j) out_flat[j] = luts[quant_idx(src[j])];
    }
}

extern "C" void kernel_launch(void* const* d_in, const int* in_sizes, int n_in,
                              void* d_out, int out_size, void* d_ws, size_t ws_size,
                              hipStream_t stream) {
    const float* src = (const float*)d_in[0];
    const int n = in_sizes[0];
    const int n4 = n >> 2;
    const dim3 block(256);

    // ws layout: [0, 32KiB) hist copies | [32KiB, 33KiB) lut | [36KiB, ...) idx
    unsigned int* copies = (unsigned int*)d_ws;
    float* lut_g = (float*)((char*)d_ws + HIST_COPIES * NBINS * 4);
    const size_t idx_off = 36864;
    unsigned int* idx4 = (unsigned int*)((char*)d_ws + idx_off);
    const bool store_idx = ws_size >= idx_off + (size_t)n;

    hipMemsetAsync(copies, 0, HIST_COPIES * NBINS * sizeof(unsigned int), stream);

    if (store_idx) {
        hist_kernel<true><<<dim3(HIST_BLOCKS), block, 0, stream>>>(src, copies, idx4, n4, n);
        lut_kernel<<<dim3(1), block, 0, stream>>>(copies, lut_g);
        gather_idx_kernel<<<dim3(GATH_BLOCKS), block, 0, stream>>>(
            idx4, lut_g, (vfloat4*)d_out, n4, n, (float*)d_out);
    } else {
        hist_kernel<false><<<dim3(HIST_BLOCKS), block, 0, stream>>>(src, copies, nullptr, n4, n);
        lut_kernel<<<dim3(1), block, 0, stream>>>(copies, lut_g);
        gather_src_kernel<<<dim3(GATH_BLOCKS), block, 0, stream>>>(
            src, lut_g, (vfloat4*)d_out, n4, n, (float*)d_out);
    }
}

// Round 9
// 118.061 us; speedup vs baseline: 1.3145x; 1.3145x over previous
//
#include <hip/hip_runtime.h>
#include <math.h>

#define NBINS 256
#define HIST_COPIES 32
#define HIST_BLOCKS 2048
#define GATH_BLOCKS 2048

typedef float vfloat4 __attribute__((ext_vector_type(4)));

__device__ __forceinline__ int quant_idx(float s) {
    // reference: clip(floor((s+1)/2*255), 0, 255)
    float t = floorf((s + 1.0f) * 0.5f * 255.0f);
    t = fminf(fmaxf(t, 0.0f), 255.0f);
    return (int)t;
}

// ---- Pass 1: LDS-privatized histogram -> 32 contention-split global copies
//      + packed-u8 idx store. nt on src (stream-through), cached idx (L3).
template <bool STORE_IDX>
__global__ __launch_bounds__(256) void hist_kernel(
    const float* __restrict__ src, unsigned int* __restrict__ copies,
    unsigned int* __restrict__ idx4_out, int n4, int n) {
    __shared__ unsigned int lh[4][NBINS];
    const int tid = threadIdx.x;
    const int wave = tid >> 6;
    for (int i = tid; i < 4 * NBINS; i += 256) ((unsigned int*)lh)[i] = 0u;
    __syncthreads();

    const int stride = gridDim.x * 256;
    const vfloat4* src4 = (const vfloat4*)src;
    for (int i = blockIdx.x * 256 + tid; i < n4; i += stride) {
        vfloat4 v = __builtin_nontemporal_load(&src4[i]);   // nt: keep L3 for idx
        int i0 = quant_idx(v.x);
        int i1 = quant_idx(v.y);
        int i2 = quant_idx(v.z);
        int i3 = quant_idx(v.w);
        atomicAdd(&lh[wave][i0], 1u);
        atomicAdd(&lh[wave][i1], 1u);
        atomicAdd(&lh[wave][i2], 1u);
        atomicAdd(&lh[wave][i3], 1u);
        if (STORE_IDX) {
            idx4_out[i] = (unsigned int)i0 | ((unsigned int)i1 << 8) |
                          ((unsigned int)i2 << 16) | ((unsigned int)i3 << 24);
        }
    }
    // tail (n % 4) — block 0, folded into its LDS hist before the flush
    if (blockIdx.x == 0 && tid == 0) {
        for (int j = n4 * 4; j < n; ++j) {
            int b = quant_idx(src[j]);
            atomicAdd(&lh[0][b], 1u);
            if (STORE_IDX) ((unsigned char*)idx4_out)[j] = (unsigned char)b;
        }
    }
    __syncthreads();
    // one atomic per bin per block, spread over 32 copies (zeroed by memset)
    unsigned int s = lh[0][tid] + lh[1][tid] + lh[2][tid] + lh[3][tid];
    if (s) atomicAdd(&copies[(blockIdx.x & (HIST_COPIES - 1)) * NBINS + tid], s);
}

// ---- per-block LUT prologue: sum 32 copies + scan + erff + lower_bound.
__device__ __forceinline__ void build_lut(
    const unsigned int* __restrict__ copies, float* luts /*LDS[256]*/,
    float* ncdf /*LDS[256]*/, unsigned int* wsum /*LDS[4]*/) {
    const int tid = threadIdx.x;
    const int wave = tid >> 6;
    unsigned int hv = 0;
#pragma unroll
    for (int c = 0; c < HIST_COPIES; ++c) hv += copies[c * NBINS + tid];
    // inclusive scan across 256 threads
    unsigned int v = hv;
    for (int d = 1; d < 64; d <<= 1) {
        unsigned int o = __shfl_up(v, d, 64);
        if ((tid & 63) >= d) v += o;
    }
    if ((tid & 63) == 63) wsum[wave] = v;
    __syncthreads();
    unsigned int add = 0;
    for (int w = 0; w < wave; ++w) add += wsum[w];
    v += add;
    const float total = (float)(wsum[0] + wsum[1] + wsum[2] + wsum[3]);
    const float sv = (float)v / total;

    // linspace(-1,1,256); norm.cdf(x,0,0.2) = 0.5*(1+erf(x/(0.2*sqrt(2))))
    const float x = ((float)tid * 2.0f - 255.0f) / 255.0f;
    const float nc = 0.5f * (1.0f + erff(x * 3.5355339059327378f));
    const float nc255 = 0.5f * (1.0f + erff(3.5355339059327378f));
    ncdf[tid] = nc / nc255;
    __syncthreads();
    // searchsorted side='left' == lower_bound
    int lo = 0, hi = NBINS;
    while (lo < hi) {
        int m = (lo + hi) >> 1;
        if (ncdf[m] < sv) lo = m + 1; else hi = m;
    }
    luts[tid] = (float)lo * (2.0f / 255.0f) - 1.0f;   // pre-apply final rescale
    __syncthreads();
}

// ---- Pass 2a: per-block LUT prologue + gather via stored u8 indices.
__global__ __launch_bounds__(256) void gather_idx_kernel(
    const unsigned int* __restrict__ idx4, const unsigned int* __restrict__ copies,
    vfloat4* __restrict__ out, int n4, int n, float* __restrict__ out_flat) {
    __shared__ float luts[NBINS];
    __shared__ float ncdf[NBINS];
    __shared__ unsigned int wsum[4];
    build_lut(copies, luts, ncdf, wsum);

    const int stride = gridDim.x * 256;
    for (int i = blockIdx.x * 256 + threadIdx.x; i < n4; i += stride) {
        unsigned int p = idx4[i];                  // cached load: L3-resident
        vfloat4 o;
        o.x = luts[p & 255u];
        o.y = luts[(p >> 8) & 255u];
        o.z = luts[(p >> 16) & 255u];
        o.w = luts[p >> 24];
        __builtin_nontemporal_store(o, &out[i]);   // nt: don't evict idx/src
    }
    if (blockIdx.x == 0 && threadIdx.x == 0) {
        const unsigned char* ib = (const unsigned char*)idx4;
        for (int j = n4 * 4; j < n; ++j) out_flat[j] = luts[ib[j]];
    }
}

// ---- Pass 2b fallback: recompute idx from source (ws too small for idx).
__global__ __launch_bounds__(256) void gather_src_kernel(
    const float* __restrict__ src, const unsigned int* __restrict__ copies,
    vfloat4* __restrict__ out, int n4, int n, float* __restrict__ out_flat) {
    __shared__ float luts[NBINS];
    __shared__ float ncdf[NBINS];
    __shared__ unsigned int wsum[4];
    build_lut(copies, luts, ncdf, wsum);

    const int stride = gridDim.x * 256;
    const vfloat4* src4 = (const vfloat4*)src;
    for (int i = blockIdx.x * 256 + threadIdx.x; i < n4; i += stride) {
        vfloat4 v = __builtin_nontemporal_load(&src4[i]);
        vfloat4 o;
        o.x = luts[quant_idx(v.x)];
        o.y = luts[quant_idx(v.y)];
        o.z = luts[quant_idx(v.z)];
        o.w = luts[quant_idx(v.w)];
        __builtin_nontemporal_store(o, &out[i]);
    }
    if (blockIdx.x == 0 && threadIdx.x == 0) {
        for (int j = n4 * 4; j < n; ++j) out_flat[j] = luts[quant_idx(src[j])];
    }
}

extern "C" void kernel_launch(void* const* d_in, const int* in_sizes, int n_in,
                              void* d_out, int out_size, void* d_ws, size_t ws_size,
                              hipStream_t stream) {
    const float* src = (const float*)d_in[0];
    const int n = in_sizes[0];
    const int n4 = n >> 2;
    const dim3 block(256);

    // ws layout: [0, 32KiB) hist copies | [36KiB, ...) packed u8 idx
    unsigned int* copies = (unsigned int*)d_ws;
    const size_t idx_off = 36864;
    unsigned int* idx4 = (unsigned int*)((char*)d_ws + idx_off);
    const bool store_idx = ws_size >= idx_off + (size_t)n;

    hipMemsetAsync(copies, 0, HIST_COPIES * NBINS * sizeof(unsigned int), stream);

    if (store_idx) {
        hist_kernel<true><<<dim3(HIST_BLOCKS), block, 0, stream>>>(src, copies, idx4, n4, n);
        gather_idx_kernel<<<dim3(GATH_BLOCKS), block, 0, stream>>>(
            idx4, copies, (vfloat4*)d_out, n4, n, (float*)d_out);
    } else {
        hist_kernel<false><<<dim3(HIST_BLOCKS), block, 0, stream>>>(src, copies, nullptr, n4, n);
        gather_src_kernel<<<dim3(GATH_BLOCKS), block, 0, stream>>>(
            src, copies, (vfloat4*)d_out, n4, n, (float*)d_out);
    }
}